// Round 1
// baseline (853.374 us; speedup 1.0000x reference)
//
#include <hip/hip_runtime.h>

typedef unsigned short u16;
typedef unsigned int u32;

using bf16x8 = __attribute__((ext_vector_type(8))) __bf16;
using f32x4  = __attribute__((ext_vector_type(4))) float;
using u16x4  = __attribute__((ext_vector_type(4))) unsigned short;

__device__ __forceinline__ f32x4 MFMA(bf16x8 a, bf16x8 b, f32x4 c) {
    return __builtin_amdgcn_mfma_f32_16x16x32_bf16(a, b, c, 0, 0, 0);
}

__device__ __forceinline__ u16 f2bf(float f) {
    u32 u = __builtin_bit_cast(u32, f);
    u = (u + 0x7FFFu + ((u >> 16) & 1u)) >> 16;
    return (u16)u;
}
__device__ __forceinline__ float bf2f(u16 h) {
    return __builtin_bit_cast(float, (u32)h << 16);
}

// ---------------- constants ----------------
#define NBATCH 16
#define NCH    512
#define NPOS   1024
#define NPADR  1156   // 34*34

// workspace layout (bytes)
static constexpr size_t OFF_XT   = 0;
static constexpr size_t OFF_YT   = OFF_XT  + (size_t)16*1024*512*2;
static constexpr size_t OFF_PJX  = OFF_YT  + (size_t)16*1024*512*2;
static constexpr size_t OFF_PJY  = OFF_PJX + (size_t)16*1024*128*2;
static constexpr size_t OFF_PV   = OFF_PJY + (size_t)16*1024*128*2;
static constexpr size_t OFF_AD   = OFF_PV  + (size_t)16*512*1024*2;
static constexpr size_t OFF_ATTN = OFF_AD  + (size_t)16*512*1024*2;
static constexpr size_t OFF_CATT = OFF_ATTN+ (size_t)16*1024*1024*2;
static constexpr size_t OFF_WQK  = OFF_CATT+ (size_t)16*1156*1024*2;
static constexpr size_t OFF_WV   = OFF_WQK + (size_t)128*512*2;
static constexpr size_t OFF_WT   = OFF_WV  + (size_t)512*512*2;
static constexpr size_t OFF_SA   = OFF_WT  + (size_t)9*512*1024*2;
static constexpr size_t OFF_OA   = OFF_SA  + (size_t)16*512*4;
static constexpr size_t OFF_TM   = OFF_OA  + (size_t)16*512*4;
static constexpr size_t SZ_CATT  = (size_t)16*1156*1024*2;

// ---------------- weight prep ----------------
__global__ __launch_bounds__(256) void k_prep_w(const float* __restrict__ Wq,
                                                const float* __restrict__ Wk,
                                                const float* __restrict__ Wv,
                                                u16* __restrict__ wqk, u16* __restrict__ wv) {
    int i = blockIdx.x * 256 + threadIdx.x;
    if (i < 128 * 512) {
        float v = (i < 64 * 512) ? Wq[i] : Wk[i - 64 * 512];
        wqk[i] = f2bf(v);
    }
    if (i < 512 * 512) wv[i] = f2bf(Wv[i]);
}

// Wc [512][1024][3][3] -> wt[tap][o][i]
__global__ __launch_bounds__(256) void k_prep_wt(const float* __restrict__ Wc, u16* __restrict__ wt) {
    int e = blockIdx.x * 256 + threadIdx.x;   // e = o*1024 + i, 524288 total
    const float* src = Wc + (size_t)e * 9;
#pragma unroll
    for (int tap = 0; tap < 9; tap++) wt[(size_t)tap * 524288 + e] = f2bf(src[tap]);
}

// ---------------- stats (AdaIN affine params) ----------------
__global__ __launch_bounds__(256) void k_stats(const float* __restrict__ x, const float* __restrict__ inp,
                                               float* __restrict__ sA, float* __restrict__ oA,
                                               float* __restrict__ tmA) {
    int row = blockIdx.x;  // b*512+c
    int t = threadIdx.x;
    const float4* xr = (const float4*)(x + (size_t)row * 1024);
    const float4* ir = (const float4*)(inp + (size_t)row * 1024);
    float4 a = xr[t], c = ir[t];
    float s1 = a.x + a.y + a.z + a.w;
    float s2 = a.x * a.x + a.y * a.y + a.z * a.z + a.w * a.w;
    float p1 = c.x + c.y + c.z + c.w;
    float p2 = c.x * c.x + c.y * c.y + c.z * c.z + c.w * c.w;
#pragma unroll
    for (int m = 32; m; m >>= 1) {
        s1 += __shfl_xor(s1, m); s2 += __shfl_xor(s2, m);
        p1 += __shfl_xor(p1, m); p2 += __shfl_xor(p2, m);
    }
    __shared__ float red[4][4];
    int wv = t >> 6;
    if ((t & 63) == 0) { red[wv][0] = s1; red[wv][1] = s2; red[wv][2] = p1; red[wv][3] = p2; }
    __syncthreads();
    if (t == 0) {
        s1 = red[0][0] + red[1][0] + red[2][0] + red[3][0];
        s2 = red[0][1] + red[1][1] + red[2][1] + red[3][1];
        p1 = red[0][2] + red[1][2] + red[2][2] + red[3][2];
        p2 = red[0][3] + red[1][3] + red[2][3] + red[3][3];
        float tm = s1 * (1.0f / 1024.0f);
        float ts = sqrtf((s2 - 1024.0f * tm * tm) * (1.0f / 1023.0f) + 1e-5f);
        float im = p1 * (1.0f / 1024.0f);
        float is = sqrtf((p2 - 1024.0f * im * im) * (1.0f / 1023.0f) + 1e-5f);
        float sc = ts / is;
        sA[row] = sc; oA[row] = tm - im * sc; tmA[row] = tm;
    }
}

// ---------------- transpose x,y -> bf16 [n][c] ----------------
__global__ __launch_bounds__(256) void k_transpose(const float* __restrict__ x, const float* __restrict__ y,
                                                   u16* __restrict__ xT, u16* __restrict__ yT) {
    __shared__ float tile[64][65];
    int b = blockIdx.y;
    int ct = blockIdx.x >> 4;    // 0..7 channel tile
    int nt = blockIdx.x & 15;    // 0..15 position tile
    const float* src = blockIdx.z ? y : x;
    u16* dst = blockIdx.z ? yT : xT;
    int c0 = ct * 64, n0 = nt * 64;
    int ln = threadIdx.x & 63, wv = threadIdx.x >> 6;
#pragma unroll
    for (int i = 0; i < 16; i++) {
        int cl = wv + i * 4;
        tile[cl][ln] = src[((size_t)(b * 512 + c0 + cl)) * 1024 + n0 + ln];
    }
    __syncthreads();
#pragma unroll
    for (int i = 0; i < 16; i++) {
        int nl = wv + i * 4;
        dst[((size_t)(b * 1024 + n0 + nl)) * 512 + c0 + ln] = f2bf(tile[ln][nl]);
    }
}

// ---------------- adained = inp*s + o  (bf16 [c][n]) ----------------
__global__ __launch_bounds__(256) void k_adain(const float* __restrict__ inp, const float* __restrict__ sA,
                                               const float* __restrict__ oA, u16* __restrict__ ad) {
    size_t i = ((size_t)blockIdx.x * 256 + threadIdx.x) * 4;
    int row = (int)(i >> 10);
    float sc = sA[row], of = oA[row];
    float4 v = *(const float4*)(inp + i);
    u16x4 r;
    r[0] = f2bf(v.x * sc + of); r[1] = f2bf(v.y * sc + of);
    r[2] = f2bf(v.z * sc + of); r[3] = f2bf(v.w * sc + of);
    *(u16x4*)(ad + i) = r;
}

// ---------------- projections: pj{x,y}T[n][128] = ([Wq;Wk] @ {x,y})^T + bias ----------------
__global__ __launch_bounds__(256) void k_proj(const u16* __restrict__ xT, const u16* __restrict__ yT,
                                              const u16* __restrict__ wqk, const float* __restrict__ bq,
                                              const float* __restrict__ bk, u16* __restrict__ pjx,
                                              u16* __restrict__ pjy) {
    int b = blockIdx.y;
    const u16* S = blockIdx.z ? yT : xT;
    u16* D = blockIdx.z ? pjy : pjx;
    int l = threadIdx.x & 63, w = threadIdx.x >> 6;
    int lr = l & 15, lg = l >> 4;
    int wm = (w >> 1) * 64;
    int nb = blockIdx.x * 128 + (w & 1) * 64;
    f32x4 zero = {0.f, 0.f, 0.f, 0.f};
    f32x4 acc[4][4];
#pragma unroll
    for (int i = 0; i < 4; i++)
#pragma unroll
        for (int j = 0; j < 4; j++) acc[i][j] = zero;
    const u16* Sbase = S + ((size_t)b * 1024 + nb + lr) * 512 + lg * 8;
    for (int kk = 0; kk < 512; kk += 32) {
        bf16x8 af[4], bb[4];
#pragma unroll
        for (int ri = 0; ri < 4; ri++)
            af[ri] = *(const bf16x8*)(wqk + (size_t)(wm + 16 * ri + lr) * 512 + kk + lg * 8);
#pragma unroll
        for (int ci = 0; ci < 4; ci++)
            bb[ci] = *(const bf16x8*)(Sbase + (size_t)(16 * ci) * 512 + kk);
#pragma unroll
        for (int ri = 0; ri < 4; ri++)
#pragma unroll
            for (int ci = 0; ci < 4; ci++) acc[ri][ci] = MFMA(af[ri], bb[ci], acc[ri][ci]);
    }
#pragma unroll
    for (int ri = 0; ri < 4; ri++) {
#pragma unroll
        for (int r = 0; r < 4; r++) {
            int cq = wm + 16 * ri + 4 * lg + r;
            float bias = (cq < 64) ? bq[cq] : bk[cq - 64];
#pragma unroll
            for (int ci = 0; ci < 4; ci++) {
                int n = nb + 16 * ci + lr;
                D[((size_t)b * 1024 + n) * 128 + cq] = f2bf(acc[ri][ci][r] + bias);
            }
        }
    }
}

// ---------------- pv = Wv @ x + bv  (bf16 [c][n]) ----------------
__global__ __launch_bounds__(256) void k_pv(const u16* __restrict__ xT, const u16* __restrict__ wv,
                                            const float* __restrict__ bv, u16* __restrict__ pv) {
    int b = blockIdx.z;
    int l = threadIdx.x & 63, w = threadIdx.x >> 6;
    int lr = l & 15, lg = l >> 4;
    int mb = blockIdx.y * 128 + (w >> 1) * 64;   // output channel
    int nb = blockIdx.x * 128 + (w & 1) * 64;    // position
    f32x4 zero = {0.f, 0.f, 0.f, 0.f};
    f32x4 acc[4][4];
#pragma unroll
    for (int i = 0; i < 4; i++)
#pragma unroll
        for (int j = 0; j < 4; j++) acc[i][j] = zero;
    const u16* Sbase = xT + ((size_t)b * 1024 + nb + lr) * 512 + lg * 8;
    for (int kk = 0; kk < 512; kk += 32) {
        bf16x8 af[4], bb[4];
#pragma unroll
        for (int ri = 0; ri < 4; ri++)
            af[ri] = *(const bf16x8*)(wv + (size_t)(mb + 16 * ri + lr) * 512 + kk + lg * 8);
#pragma unroll
        for (int ci = 0; ci < 4; ci++)
            bb[ci] = *(const bf16x8*)(Sbase + (size_t)(16 * ci) * 512 + kk);
#pragma unroll
        for (int ri = 0; ri < 4; ri++)
#pragma unroll
            for (int ci = 0; ci < 4; ci++) acc[ri][ci] = MFMA(af[ri], bb[ci], acc[ri][ci]);
    }
#pragma unroll
    for (int ri = 0; ri < 4; ri++) {
#pragma unroll
        for (int r = 0; r < 4; r++) {
            int co = mb + 16 * ri + 4 * lg + r;
            float bias = bv[co];
#pragma unroll
            for (int ci = 0; ci < 4; ci++) {
                int n = nb + 16 * ci + lr;
                pv[((size_t)b * 512 + co) * 1024 + n] = f2bf(acc[ri][ci][r] + bias);
            }
        }
    }
}

// ---------------- score + softmax (two-pass, all in-register) ----------------
// attn[b][q][k] = softmax_k( (Q K^T)/8 ), Q = qT[:,0:64], K = kT[:,64:128]
__global__ __launch_bounds__(256) void k_score(const u16* __restrict__ qT, const u16* __restrict__ kT,
                                               u16* __restrict__ attn) {
    int g = blockIdx.x * 4 + (threadIdx.x >> 6);
    int b = g >> 6, rb = g & 63;
    int l = threadIdx.x & 63, lr = l & 15, lg = l >> 4;
    int mb = rb * 16;
    const u16* qbase = qT + ((size_t)b * 1024 + mb + lr) * 128 + lg * 8;
    bf16x8 a0 = *(const bf16x8*)(qbase);
    bf16x8 a1 = *(const bf16x8*)(qbase + 32);
    const u16* kbase = kT + ((size_t)b * 1024 + lr) * 128 + 64 + lg * 8;
    f32x4 zero = {0.f, 0.f, 0.f, 0.f};
    float mrun[4] = {-1e30f, -1e30f, -1e30f, -1e30f};
    float srun[4] = {0.f, 0.f, 0.f, 0.f};
    for (int cf = 0; cf < 64; cf++) {
        bf16x8 b0 = *(const bf16x8*)(kbase + (size_t)cf * 16 * 128);
        bf16x8 b1 = *(const bf16x8*)(kbase + (size_t)cf * 16 * 128 + 32);
        f32x4 acc = zero;
        acc = MFMA(a0, b0, acc);
        acc = MFMA(a1, b1, acc);
#pragma unroll
        for (int r = 0; r < 4; r++) {
            float v = acc[r] * 0.125f;
            float mn = fmaxf(mrun[r], v);
            srun[r] = srun[r] * __expf(mrun[r] - mn) + __expf(v - mn);
            mrun[r] = mn;
        }
    }
#pragma unroll
    for (int m = 1; m < 16; m <<= 1) {
#pragma unroll
        for (int r = 0; r < 4; r++) {
            float mo = __shfl_xor(mrun[r], m);
            float so = __shfl_xor(srun[r], m);
            float mn = fmaxf(mrun[r], mo);
            srun[r] = srun[r] * __expf(mrun[r] - mn) + so * __expf(mo - mn);
            mrun[r] = mn;
        }
    }
    float inv[4];
#pragma unroll
    for (int r = 0; r < 4; r++) inv[r] = 1.0f / srun[r];
    for (int cf = 0; cf < 64; cf++) {
        bf16x8 b0 = *(const bf16x8*)(kbase + (size_t)cf * 16 * 128);
        bf16x8 b1 = *(const bf16x8*)(kbase + (size_t)cf * 16 * 128 + 32);
        f32x4 acc = zero;
        acc = MFMA(a0, b0, acc);
        acc = MFMA(a1, b1, acc);
#pragma unroll
        for (int r = 0; r < 4; r++) {
            float v = __expf(acc[r] * 0.125f - mrun[r]) * inv[r];
            attn[((size_t)b * 1024 + mb + 4 * lg + r) * 1024 + cf * 16 + lr] = f2bf(v);
        }
    }
}

// ---------------- value GEMMs -> catT (padded, position-major) ----------------
// VAR=0: x_update = (1-beta)*x + beta*(attn @ pv^T)       -> catT[..][0..511]
// VAR=1: rev = (1-alpha)*(1024*tmean - attn @ ad^T) + alpha*ad -> catT[..][512..1023]
template <int VAR>
__global__ __launch_bounds__(256) void k_value(const u16* __restrict__ attn, const u16* __restrict__ V,
                                               const u16* __restrict__ xT, const float* __restrict__ tmA,
                                               const float* __restrict__ scal, u16* __restrict__ catT) {
    int b = blockIdx.z;
    int l = threadIdx.x & 63, w = threadIdx.x >> 6;
    int lr = l & 15, lg = l >> 4;
    int mb = blockIdx.x * 128 + (w >> 1) * 64;  // position (query)
    int cb = blockIdx.y * 128 + (w & 1) * 64;   // channel
    f32x4 zero = {0.f, 0.f, 0.f, 0.f};
    f32x4 acc[4][4];
#pragma unroll
    for (int i = 0; i < 4; i++)
#pragma unroll
        for (int j = 0; j < 4; j++) acc[i][j] = zero;
    const u16* Ab = attn + ((size_t)b * 1024 + mb + lr) * 1024 + lg * 8;
    const u16* Bb = V + ((size_t)b * 512 + cb + lr) * 1024 + lg * 8;
    for (int kk = 0; kk < 1024; kk += 32) {
        bf16x8 af[4], bb[4];
#pragma unroll
        for (int i = 0; i < 4; i++) af[i] = *(const bf16x8*)(Ab + (size_t)(16 * i) * 1024 + kk);
#pragma unroll
        for (int i = 0; i < 4; i++) bb[i] = *(const bf16x8*)(Bb + (size_t)(16 * i) * 1024 + kk);
#pragma unroll
        for (int ri = 0; ri < 4; ri++)
#pragma unroll
            for (int ci = 0; ci < 4; ci++) acc[ri][ci] = MFMA(af[ri], bb[ci], acc[ri][ci]);
    }
    float sc = scal[0];
#pragma unroll
    for (int ri = 0; ri < 4; ri++) {
#pragma unroll
        for (int r = 0; r < 4; r++) {
            int m = mb + 16 * ri + 4 * lg + r;
            int pidx = ((m >> 5) + 1) * 34 + (m & 31) + 1;
#pragma unroll
            for (int ci = 0; ci < 4; ci++) {
                int c = cb + 16 * ci + lr;
                float av = acc[ri][ci][r];
                float res;
                if (VAR == 0) {
                    float xv = bf2f(xT[((size_t)b * 1024 + m) * 512 + c]);
                    res = (1.f - sc) * xv + sc * av;
                } else {
                    float tm = tmA[b * 512 + c];
                    float adv = bf2f(V[((size_t)b * 512 + c) * 1024 + m]);
                    res = (1.f - sc) * (1024.f * tm - av) + sc * adv;
                }
                catT[((size_t)b * NPADR + pidx) * 1024 + (VAR ? 512 : 0) + c] = f2bf(res);
            }
        }
    }
}

// ---------------- 3x3 conv (implicit GEMM, tap-major K) + bias + LeakyReLU ----------------
__global__ __launch_bounds__(256) void k_conv(const u16* __restrict__ wt, const u16* __restrict__ catT,
                                              const float* __restrict__ bc, float* __restrict__ out) {
    int b = blockIdx.z;
    int l = threadIdx.x & 63, w = threadIdx.x >> 6;
    int lr = l & 15, lg = l >> 4;
    int ob = blockIdx.x * 128 + (w >> 1) * 64;  // output channel
    int pb = blockIdx.y * 128 + (w & 1) * 64;   // position
    int pidx[4];
#pragma unroll
    for (int ci = 0; ci < 4; ci++) {
        int p = pb + 16 * ci + lr;
        pidx[ci] = ((p >> 5) + 1) * 34 + (p & 31) + 1;
    }
    f32x4 zero = {0.f, 0.f, 0.f, 0.f};
    f32x4 acc[4][4];
#pragma unroll
    for (int i = 0; i < 4; i++)
#pragma unroll
        for (int j = 0; j < 4; j++) acc[i][j] = zero;
    const u16* Cb = catT + (size_t)b * NPADR * 1024;
#pragma unroll 1
    for (int tap = 0; tap < 9; tap++) {
        int drow = (tap / 3 - 1) * 34 + (tap % 3 - 1);
        const u16* Ab = wt + ((size_t)(tap * 512 + ob + lr)) * 1024 + lg * 8;
        for (int kk = 0; kk < 1024; kk += 32) {
            bf16x8 af[4], bb[4];
#pragma unroll
            for (int i = 0; i < 4; i++) af[i] = *(const bf16x8*)(Ab + (size_t)(16 * i) * 1024 + kk);
#pragma unroll
            for (int i = 0; i < 4; i++) bb[i] = *(const bf16x8*)(Cb + (size_t)(pidx[i] + drow) * 1024 + kk + lg * 8);
#pragma unroll
            for (int ri = 0; ri < 4; ri++)
#pragma unroll
                for (int ci = 0; ci < 4; ci++) acc[ri][ci] = MFMA(af[ri], bb[ci], acc[ri][ci]);
        }
    }
#pragma unroll
    for (int ri = 0; ri < 4; ri++) {
#pragma unroll
        for (int r = 0; r < 4; r++) {
            int o = ob + 16 * ri + 4 * lg + r;
            float bias = bc[o];
#pragma unroll
            for (int ci = 0; ci < 4; ci++) {
                int p = pb + 16 * ci + lr;
                float v = acc[ri][ci][r] + bias;
                v = (v >= 0.f) ? v : 0.2f * v;
                out[((size_t)b * 512 + o) * 1024 + p] = v;
            }
        }
    }
}

// ---------------- launch ----------------
extern "C" void kernel_launch(void* const* d_in, const int* in_sizes, int n_in,
                              void* d_out, int out_size, void* d_ws, size_t ws_size,
                              hipStream_t stream) {
    (void)in_sizes; (void)n_in; (void)out_size; (void)ws_size;
    const float* inp = (const float*)d_in[0];
    const float* x   = (const float*)d_in[1];
    const float* y   = (const float*)d_in[2];
    const float* Wq  = (const float*)d_in[3];
    const float* bq  = (const float*)d_in[4];
    const float* Wk  = (const float*)d_in[5];
    const float* bk  = (const float*)d_in[6];
    const float* Wv  = (const float*)d_in[7];
    const float* bv  = (const float*)d_in[8];
    const float* Wc  = (const float*)d_in[9];
    const float* bc  = (const float*)d_in[10];
    const float* alpha = (const float*)d_in[11];
    const float* beta  = (const float*)d_in[12];
    float* out = (float*)d_out;

    char* ws = (char*)d_ws;
    u16* xT   = (u16*)(ws + OFF_XT);
    u16* yT   = (u16*)(ws + OFF_YT);
    u16* pjx  = (u16*)(ws + OFF_PJX);
    u16* pjy  = (u16*)(ws + OFF_PJY);
    u16* pv   = (u16*)(ws + OFF_PV);
    u16* ad   = (u16*)(ws + OFF_AD);
    u16* attn = (u16*)(ws + OFF_ATTN);
    u16* catT = (u16*)(ws + OFF_CATT);
    u16* wqk  = (u16*)(ws + OFF_WQK);
    u16* wv   = (u16*)(ws + OFF_WV);
    u16* wt   = (u16*)(ws + OFF_WT);
    float* sA  = (float*)(ws + OFF_SA);
    float* oA  = (float*)(ws + OFF_OA);
    float* tmA = (float*)(ws + OFF_TM);

    hipMemsetAsync(catT, 0, SZ_CATT, stream);   // zero border = SAME padding
    k_prep_w<<<1024, 256, 0, stream>>>(Wq, Wk, Wv, wqk, wv);
    k_prep_wt<<<2048, 256, 0, stream>>>(Wc, wt);
    k_stats<<<8192, 256, 0, stream>>>(x, inp, sA, oA, tmA);
    k_transpose<<<dim3(128, 16, 2), 256, 0, stream>>>(x, y, xT, yT);
    k_adain<<<8192, 256, 0, stream>>>(inp, sA, oA, ad);
    k_proj<<<dim3(8, 16, 2), 256, 0, stream>>>(xT, yT, wqk, bq, bk, pjx, pjy);
    k_pv<<<dim3(8, 4, 16), 256, 0, stream>>>(xT, wv, bv, pv);
    // identity attention: Q from x, K from y
    k_score<<<256, 256, 0, stream>>>(pjx, pjy, attn);
    k_value<0><<<dim3(8, 4, 16), 256, 0, stream>>>(attn, pv, xT, tmA, beta, catT);
    // pose attention: Q from y, K from x (reuses attn buffer, stream-ordered)
    k_score<<<256, 256, 0, stream>>>(pjy, pjx, attn);
    k_value<1><<<dim3(8, 4, 16), 256, 0, stream>>>(attn, ad, xT, tmA, alpha, catT);
    k_conv<<<dim3(4, 8, 16), 256, 0, stream>>>(wt, catT, bc, out);
}

// Round 2
// 482.584 us; speedup vs baseline: 1.7683x; 1.7683x over previous
//
#include <hip/hip_runtime.h>

typedef unsigned short u16;
typedef unsigned int u32;

using bf16x8 = __attribute__((ext_vector_type(8))) __bf16;
using f32x4  = __attribute__((ext_vector_type(4))) float;
using u16x4  = __attribute__((ext_vector_type(4))) unsigned short;

__device__ __forceinline__ f32x4 MFMA(bf16x8 a, bf16x8 b, f32x4 c) {
    return __builtin_amdgcn_mfma_f32_16x16x32_bf16(a, b, c, 0, 0, 0);
}

__device__ __forceinline__ u16 f2bf(float f) {
    u32 u = __builtin_bit_cast(u32, f);
    u = (u + 0x7FFFu + ((u >> 16) & 1u)) >> 16;
    return (u16)u;
}
__device__ __forceinline__ float bf2f(u16 h) {
    return __builtin_bit_cast(float, (u32)h << 16);
}

typedef const __attribute__((address_space(1))) unsigned int* gp_t;
typedef __attribute__((address_space(3))) unsigned int* lp_t;

// async global->LDS, 16B per lane; lds dest = wave-uniform base + lane*16
__device__ __forceinline__ void gload16(const void* g, void* l) {
    __builtin_amdgcn_global_load_lds((gp_t)g, (lp_t)l, 16, 0, 0);
}

// ---------------- constants ----------------
#define NBATCH 16
#define NCH    512
#define NPOS   1024
#define NPADR  1156   // 34*34

// workspace layout (bytes)
static constexpr size_t OFF_XT   = 0;
static constexpr size_t OFF_YT   = OFF_XT  + (size_t)16*1024*512*2;
static constexpr size_t OFF_PJX  = OFF_YT  + (size_t)16*1024*512*2;
static constexpr size_t OFF_PJY  = OFF_PJX + (size_t)16*1024*128*2;
static constexpr size_t OFF_PV   = OFF_PJY + (size_t)16*1024*128*2;
static constexpr size_t OFF_AD   = OFF_PV  + (size_t)16*512*1024*2;
static constexpr size_t OFF_ATTN = OFF_AD  + (size_t)16*512*1024*2;
static constexpr size_t OFF_CATT = OFF_ATTN+ (size_t)16*1024*1024*2;
static constexpr size_t OFF_WQK  = OFF_CATT+ (size_t)16*1156*1024*2;
static constexpr size_t OFF_WV   = OFF_WQK + (size_t)128*512*2;
static constexpr size_t OFF_WT   = OFF_WV  + (size_t)512*512*2;
static constexpr size_t OFF_SA   = OFF_WT  + (size_t)9*512*1024*2;
static constexpr size_t OFF_OA   = OFF_SA  + (size_t)16*512*4;
static constexpr size_t OFF_TM   = OFF_OA  + (size_t)16*512*4;
static constexpr size_t SZ_CATT  = (size_t)16*1156*1024*2;

// ---------------- weight prep ----------------
__global__ __launch_bounds__(256) void k_prep_w(const float* __restrict__ Wq,
                                                const float* __restrict__ Wk,
                                                const float* __restrict__ Wv,
                                                u16* __restrict__ wqk, u16* __restrict__ wv) {
    int i = blockIdx.x * 256 + threadIdx.x;
    if (i < 128 * 512) {
        float v = (i < 64 * 512) ? Wq[i] : Wk[i - 64 * 512];
        wqk[i] = f2bf(v);
    }
    if (i < 512 * 512) wv[i] = f2bf(Wv[i]);
}

// Wc [512][1024][3][3] -> wt[tap][o][i]
__global__ __launch_bounds__(256) void k_prep_wt(const float* __restrict__ Wc, u16* __restrict__ wt) {
    int e = blockIdx.x * 256 + threadIdx.x;   // e = o*1024 + i, 524288 total
    const float* src = Wc + (size_t)e * 9;
#pragma unroll
    for (int tap = 0; tap < 9; tap++) wt[(size_t)tap * 524288 + e] = f2bf(src[tap]);
}

// ---------------- stats (AdaIN affine params) ----------------
__global__ __launch_bounds__(256) void k_stats(const float* __restrict__ x, const float* __restrict__ inp,
                                               float* __restrict__ sA, float* __restrict__ oA,
                                               float* __restrict__ tmA) {
    int row = blockIdx.x;  // b*512+c
    int t = threadIdx.x;
    const float4* xr = (const float4*)(x + (size_t)row * 1024);
    const float4* ir = (const float4*)(inp + (size_t)row * 1024);
    float4 a = xr[t], c = ir[t];
    float s1 = a.x + a.y + a.z + a.w;
    float s2 = a.x * a.x + a.y * a.y + a.z * a.z + a.w * a.w;
    float p1 = c.x + c.y + c.z + c.w;
    float p2 = c.x * c.x + c.y * c.y + c.z * c.z + c.w * c.w;
#pragma unroll
    for (int m = 32; m; m >>= 1) {
        s1 += __shfl_xor(s1, m); s2 += __shfl_xor(s2, m);
        p1 += __shfl_xor(p1, m); p2 += __shfl_xor(p2, m);
    }
    __shared__ float red[4][4];
    int wv = t >> 6;
    if ((t & 63) == 0) { red[wv][0] = s1; red[wv][1] = s2; red[wv][2] = p1; red[wv][3] = p2; }
    __syncthreads();
    if (t == 0) {
        s1 = red[0][0] + red[1][0] + red[2][0] + red[3][0];
        s2 = red[0][1] + red[1][1] + red[2][1] + red[3][1];
        p1 = red[0][2] + red[1][2] + red[2][2] + red[3][2];
        p2 = red[0][3] + red[1][3] + red[2][3] + red[3][3];
        float tm = s1 * (1.0f / 1024.0f);
        float ts = sqrtf((s2 - 1024.0f * tm * tm) * (1.0f / 1023.0f) + 1e-5f);
        float im = p1 * (1.0f / 1024.0f);
        float is = sqrtf((p2 - 1024.0f * im * im) * (1.0f / 1023.0f) + 1e-5f);
        float sc = ts / is;
        sA[row] = sc; oA[row] = tm - im * sc; tmA[row] = tm;
    }
}

// ---------------- transpose x,y -> bf16 [n][c] ----------------
__global__ __launch_bounds__(256) void k_transpose(const float* __restrict__ x, const float* __restrict__ y,
                                                   u16* __restrict__ xT, u16* __restrict__ yT) {
    __shared__ float tile[64][65];
    int b = blockIdx.y;
    int ct = blockIdx.x >> 4;    // 0..7 channel tile
    int nt = blockIdx.x & 15;    // 0..15 position tile
    const float* src = blockIdx.z ? y : x;
    u16* dst = blockIdx.z ? yT : xT;
    int c0 = ct * 64, n0 = nt * 64;
    int ln = threadIdx.x & 63, wv = threadIdx.x >> 6;
#pragma unroll
    for (int i = 0; i < 16; i++) {
        int cl = wv + i * 4;
        tile[cl][ln] = src[((size_t)(b * 512 + c0 + cl)) * 1024 + n0 + ln];
    }
    __syncthreads();
#pragma unroll
    for (int i = 0; i < 16; i++) {
        int nl = wv + i * 4;
        dst[((size_t)(b * 1024 + n0 + nl)) * 512 + c0 + ln] = f2bf(tile[ln][nl]);
    }
}

// ---------------- adained = inp*s + o  (bf16 [c][n]) ----------------
__global__ __launch_bounds__(256) void k_adain(const float* __restrict__ inp, const float* __restrict__ sA,
                                               const float* __restrict__ oA, u16* __restrict__ ad) {
    size_t i = ((size_t)blockIdx.x * 256 + threadIdx.x) * 4;
    int row = (int)(i >> 10);
    float sc = sA[row], of = oA[row];
    float4 v = *(const float4*)(inp + i);
    u16x4 r;
    r[0] = f2bf(v.x * sc + of); r[1] = f2bf(v.y * sc + of);
    r[2] = f2bf(v.z * sc + of); r[3] = f2bf(v.w * sc + of);
    *(u16x4*)(ad + i) = r;
}

// ---------------- projections (direct-global fragments; small) ----------------
__global__ __launch_bounds__(256) void k_proj(const u16* __restrict__ xT, const u16* __restrict__ yT,
                                              const u16* __restrict__ wqk, const float* __restrict__ bq,
                                              const float* __restrict__ bk, u16* __restrict__ pjx,
                                              u16* __restrict__ pjy) {
    int b = blockIdx.y;
    const u16* S = blockIdx.z ? yT : xT;
    u16* D = blockIdx.z ? pjy : pjx;
    int l = threadIdx.x & 63, w = threadIdx.x >> 6;
    int lr = l & 15, lg = l >> 4;
    int wm = (w >> 1) * 64;
    int nb = blockIdx.x * 128 + (w & 1) * 64;
    f32x4 zero = {0.f, 0.f, 0.f, 0.f};
    f32x4 acc[4][4];
#pragma unroll
    for (int i = 0; i < 4; i++)
#pragma unroll
        for (int j = 0; j < 4; j++) acc[i][j] = zero;
    const u16* Sbase = S + ((size_t)b * 1024 + nb + lr) * 512 + lg * 8;
    for (int kk = 0; kk < 512; kk += 32) {
        bf16x8 af[4], bb[4];
#pragma unroll
        for (int ri = 0; ri < 4; ri++)
            af[ri] = *(const bf16x8*)(wqk + (size_t)(wm + 16 * ri + lr) * 512 + kk + lg * 8);
#pragma unroll
        for (int ci = 0; ci < 4; ci++)
            bb[ci] = *(const bf16x8*)(Sbase + (size_t)(16 * ci) * 512 + kk);
#pragma unroll
        for (int ri = 0; ri < 4; ri++)
#pragma unroll
            for (int ci = 0; ci < 4; ci++) acc[ri][ci] = MFMA(af[ri], bb[ci], acc[ri][ci]);
    }
#pragma unroll
    for (int ri = 0; ri < 4; ri++) {
#pragma unroll
        for (int r = 0; r < 4; r++) {
            int cq = wm + 16 * ri + 4 * lg + r;
            float bias = (cq < 64) ? bq[cq] : bk[cq - 64];
#pragma unroll
            for (int ci = 0; ci < 4; ci++) {
                int n = nb + 16 * ci + lr;
                D[((size_t)b * 1024 + n) * 128 + cq] = f2bf(acc[ri][ci][r] + bias);
            }
        }
    }
}

// ---------------- staged 128x128 GEMM core (m97 structure) ----------------
// A: [M][K] row-major (LDA), B: [N][K] row-major (LDB); C = A * B^T
// LDS layout per 8KB buffer: [4 kgroup][128 row][16B], conflict-light b128 reads.
template <int KTOT, int LDA, int LDB>
__device__ __forceinline__ void gemm128(const u16* __restrict__ Aorig, const u16* __restrict__ Borig,
                                        f32x4 (&acc)[4][4]) {
    __shared__ __align__(16) u16 lds[16384];  // A0,A1 @0/8KB ; B0,B1 @16/24KB
    const int tid = threadIdx.x;
    const int l = tid & 63, w = tid >> 6;
    const int lr = l & 15, lg = l >> 4;
    const int moff = (w >> 1) * 64, coff = (w & 1) * 64;
    char* ldsb = (char*)lds;
    auto stage = [&](const u16* orig, int ldx, int bufByte) {
#pragma unroll
        for (int it = 0; it < 2; it++) {
            int slot = it * 256 + tid;
            gload16(orig + (size_t)(slot & 127) * ldx + (slot >> 7) * 8,
                    ldsb + bufByte + it * 4096 + w * 1024);
        }
    };
    stage(Aorig, LDA, 0);
    stage(Borig, LDB, 16384);
    __syncthreads();
    int pa = 0;
#pragma unroll 1
    for (int kI = 0; kI < KTOT / 32; kI++) {
        if (kI + 1 < KTOT / 32) {
            stage(Aorig + (kI + 1) * 32, LDA, (pa ^ 1) * 8192);
            stage(Borig + (kI + 1) * 32, LDB, 16384 + (pa ^ 1) * 8192);
        }
        const char* A = ldsb + pa * 8192;
        const char* B = ldsb + 16384 + pa * 8192;
        bf16x8 af[4], bb[4];
#pragma unroll
        for (int i = 0; i < 4; i++) af[i] = *(const bf16x8*)(A + lg * 2048 + (moff + 16 * i + lr) * 16);
#pragma unroll
        for (int i = 0; i < 4; i++) bb[i] = *(const bf16x8*)(B + lg * 2048 + (coff + 16 * i + lr) * 16);
#pragma unroll
        for (int ri = 0; ri < 4; ri++)
#pragma unroll
            for (int ci = 0; ci < 4; ci++) acc[ri][ci] = MFMA(af[ri], bb[ci], acc[ri][ci]);
        __syncthreads();
        pa ^= 1;
    }
}

// ---------------- pv = Wv @ x + bv  (bf16 [c][n]) ----------------
__global__ __launch_bounds__(256) void k_pv(const u16* __restrict__ xT, const u16* __restrict__ wv,
                                            const float* __restrict__ bv, u16* __restrict__ pv) {
    int b = blockIdx.z;
    int mb = blockIdx.y * 128;   // output channel tile
    int nb = blockIdx.x * 128;   // position tile
    f32x4 acc[4][4];
#pragma unroll
    for (int i = 0; i < 4; i++)
#pragma unroll
        for (int j = 0; j < 4; j++) acc[i][j] = f32x4{0.f, 0.f, 0.f, 0.f};
    gemm128<512, 512, 512>(wv + (size_t)mb * 512, xT + ((size_t)b * 1024 + nb) * 512, acc);
    int l = threadIdx.x & 63, w = threadIdx.x >> 6;
    int lr = l & 15, lg = l >> 4;
    int moff = (w >> 1) * 64, coff = (w & 1) * 64;
#pragma unroll
    for (int ri = 0; ri < 4; ri++) {
#pragma unroll
        for (int r = 0; r < 4; r++) {
            int co = mb + moff + 16 * ri + 4 * lg + r;
            float bias = bv[co];
#pragma unroll
            for (int ci = 0; ci < 4; ci++) {
                int n = nb + coff + 16 * ci + lr;
                pv[((size_t)b * 512 + co) * 1024 + n] = f2bf(acc[ri][ci][r] + bias);
            }
        }
    }
}

// ---------------- score + softmax (two-pass, all in-register) ----------------
__global__ __launch_bounds__(256) void k_score(const u16* __restrict__ qT, const u16* __restrict__ kT,
                                               u16* __restrict__ attn) {
    int g = blockIdx.x * 4 + (threadIdx.x >> 6);
    int b = g >> 6, rb = g & 63;
    int l = threadIdx.x & 63, lr = l & 15, lg = l >> 4;
    int mb = rb * 16;
    const u16* qbase = qT + ((size_t)b * 1024 + mb + lr) * 128 + lg * 8;
    bf16x8 a0 = *(const bf16x8*)(qbase);
    bf16x8 a1 = *(const bf16x8*)(qbase + 32);
    const u16* kbase = kT + ((size_t)b * 1024 + lr) * 128 + 64 + lg * 8;
    f32x4 zero = {0.f, 0.f, 0.f, 0.f};
    float mrun[4] = {-1e30f, -1e30f, -1e30f, -1e30f};
    float srun[4] = {0.f, 0.f, 0.f, 0.f};
    for (int cf = 0; cf < 64; cf++) {
        bf16x8 b0 = *(const bf16x8*)(kbase + (size_t)cf * 16 * 128);
        bf16x8 b1 = *(const bf16x8*)(kbase + (size_t)cf * 16 * 128 + 32);
        f32x4 acc = zero;
        acc = MFMA(a0, b0, acc);
        acc = MFMA(a1, b1, acc);
#pragma unroll
        for (int r = 0; r < 4; r++) {
            float v = acc[r] * 0.125f;
            float mn = fmaxf(mrun[r], v);
            srun[r] = srun[r] * __expf(mrun[r] - mn) + __expf(v - mn);
            mrun[r] = mn;
        }
    }
#pragma unroll
    for (int m = 1; m < 16; m <<= 1) {
#pragma unroll
        for (int r = 0; r < 4; r++) {
            float mo = __shfl_xor(mrun[r], m);
            float so = __shfl_xor(srun[r], m);
            float mn = fmaxf(mrun[r], mo);
            srun[r] = srun[r] * __expf(mrun[r] - mn) + so * __expf(mo - mn);
            mrun[r] = mn;
        }
    }
    float inv[4];
#pragma unroll
    for (int r = 0; r < 4; r++) inv[r] = 1.0f / srun[r];
    for (int cf = 0; cf < 64; cf++) {
        bf16x8 b0 = *(const bf16x8*)(kbase + (size_t)cf * 16 * 128);
        bf16x8 b1 = *(const bf16x8*)(kbase + (size_t)cf * 16 * 128 + 32);
        f32x4 acc = zero;
        acc = MFMA(a0, b0, acc);
        acc = MFMA(a1, b1, acc);
#pragma unroll
        for (int r = 0; r < 4; r++) {
            float v = __expf(acc[r] * 0.125f - mrun[r]) * inv[r];
            attn[((size_t)b * 1024 + mb + 4 * lg + r) * 1024 + cf * 16 + lr] = f2bf(v);
        }
    }
}

// ---------------- value GEMMs -> catT (padded, position-major) ----------------
template <int VAR>
__global__ __launch_bounds__(256) void k_value(const u16* __restrict__ attn, const u16* __restrict__ V,
                                               const u16* __restrict__ xT, const float* __restrict__ tmA,
                                               const float* __restrict__ scal, u16* __restrict__ catT) {
    int b = blockIdx.z;
    int mb = blockIdx.x * 128;  // position (query) tile
    int cb = blockIdx.y * 128;  // channel tile
    f32x4 acc[4][4];
#pragma unroll
    for (int i = 0; i < 4; i++)
#pragma unroll
        for (int j = 0; j < 4; j++) acc[i][j] = f32x4{0.f, 0.f, 0.f, 0.f};
    gemm128<1024, 1024, 1024>(attn + ((size_t)b * 1024 + mb) * 1024,
                              V + ((size_t)b * 512 + cb) * 1024, acc);
    int l = threadIdx.x & 63, w = threadIdx.x >> 6;
    int lr = l & 15, lg = l >> 4;
    int moff = (w >> 1) * 64, coff = (w & 1) * 64;
    float sc = scal[0];
#pragma unroll
    for (int ri = 0; ri < 4; ri++) {
#pragma unroll
        for (int r = 0; r < 4; r++) {
            int m = mb + moff + 16 * ri + 4 * lg + r;
            int pidx = ((m >> 5) + 1) * 34 + (m & 31) + 1;
#pragma unroll
            for (int ci = 0; ci < 4; ci++) {
                int c = cb + coff + 16 * ci + lr;
                float av = acc[ri][ci][r];
                float res;
                if (VAR == 0) {
                    float xv = bf2f(xT[((size_t)b * 1024 + m) * 512 + c]);
                    res = (1.f - sc) * xv + sc * av;
                } else {
                    float tm = tmA[b * 512 + c];
                    float adv = bf2f(V[((size_t)b * 512 + c) * 1024 + m]);
                    res = (1.f - sc) * (1024.f * tm - av) + sc * adv;
                }
                catT[((size_t)b * NPADR + pidx) * 1024 + (VAR ? 512 : 0) + c] = f2bf(res);
            }
        }
    }
}

// ---------------- 3x3 conv: staged implicit GEMM with shared halo B ----------------
// Per 32-ch K-step: stage 6x34-row halo of catT once (rows contiguous!), reuse
// across 9 taps; weight A-tile (8KB) staged per (tap,ck), double-buffered.
__global__ __launch_bounds__(256) void k_conv(const u16* __restrict__ wt, const u16* __restrict__ catT,
                                              const float* __restrict__ bc, float* __restrict__ out) {
    // LDS: A0 @0, A1 @8KB (u16 idx 4096), B0 @16KB (idx 8192), B1 @32KB (idx 16384)
    __shared__ __align__(16) u16 lds[24576];
    char* ldsb = (char*)lds;
    const int tid = threadIdx.x;
    const int l = tid & 63, w = tid >> 6;
    const int lr = l & 15, lg = l >> 4;
    const int b = blockIdx.z;
    const int ob = blockIdx.x * 128;   // out-channel tile
    const int pb = blockIdx.y * 128;   // position tile (4 image rows)
    const int r0 = blockIdx.y * 4;     // first padded halo row
    const int ooff = (w >> 1) * 64, poff = (w & 1) * 64;
    const u16* catB = catT + (size_t)b * NPADR * 1024 + (size_t)r0 * 34 * 1024;

    auto stageB = [&](int ckb, int bsel) {
        char* base = ldsb + 16384 + bsel * 16384;
        const u16* src0 = catB + ckb;
#pragma unroll
        for (int it = 0; it < 4; it++) {
            if (tid < 204)
                gload16(src0 + (size_t)tid * 1024 + it * 8, base + it * 4096 + w * 1024);
        }
    };
    auto stageA = [&](int tap, int ckb, int asel) {
        char* base = ldsb + asel * 8192;
        const u16* src0 = wt + ((size_t)tap * 512 + ob) * 1024 + ckb;
#pragma unroll
        for (int it = 0; it < 2; it++) {
            int slot = it * 256 + tid;
            gload16(src0 + (size_t)(slot & 127) * 1024 + (slot >> 7) * 8,
                    base + it * 4096 + w * 1024);
        }
    };

    // read offsets
    int aoff[4], rbase[4];
#pragma unroll
    for (int i = 0; i < 4; i++) {
        aoff[i] = lg * 2048 + (ooff + 16 * i + lr) * 16;
        int p = poff + 16 * i + lr;
        rbase[i] = ((p >> 5) + 1) * 34 + (p & 31) + 1;
    }

    f32x4 acc[4][4];
#pragma unroll
    for (int i = 0; i < 4; i++)
#pragma unroll
        for (int j = 0; j < 4; j++) acc[i][j] = f32x4{0.f, 0.f, 0.f, 0.f};

    stageB(0, 0);
    stageA(0, 0, 0);
    __syncthreads();
    int pa = 0;
#pragma unroll 1
    for (int ckI = 0; ckI < 32; ckI++) {
#pragma unroll
        for (int tap = 0; tap < 9; tap++) {
            if (tap == 8) {
                if (ckI + 1 < 32) {
                    stageB((ckI + 1) * 32, (ckI + 1) & 1);
                    stageA(0, (ckI + 1) * 32, pa ^ 1);
                }
            } else {
                stageA(tap + 1, ckI * 32, pa ^ 1);
            }
            const char* A = ldsb + pa * 8192;
            const char* B = ldsb + 16384 + (ckI & 1) * 16384;
            const int drow = (tap / 3 - 1) * 34 + (tap % 3 - 1);
            bf16x8 af[4], bb[4];
#pragma unroll
            for (int i = 0; i < 4; i++) af[i] = *(const bf16x8*)(A + aoff[i]);
#pragma unroll
            for (int i = 0; i < 4; i++) bb[i] = *(const bf16x8*)(B + lg * 4096 + (rbase[i] + drow) * 16);
#pragma unroll
            for (int ri = 0; ri < 4; ri++)
#pragma unroll
                for (int ci = 0; ci < 4; ci++) acc[ri][ci] = MFMA(af[ri], bb[ci], acc[ri][ci]);
            __syncthreads();
            pa ^= 1;
        }
    }
#pragma unroll
    for (int ri = 0; ri < 4; ri++) {
#pragma unroll
        for (int r = 0; r < 4; r++) {
            int o = ob + ooff + 16 * ri + 4 * lg + r;
            float bias = bc[o];
#pragma unroll
            for (int ci = 0; ci < 4; ci++) {
                int p = pb + poff + 16 * ci + lr;
                float v = acc[ri][ci][r] + bias;
                v = (v >= 0.f) ? v : 0.2f * v;
                out[((size_t)b * 512 + o) * 1024 + p] = v;
            }
        }
    }
}

// ---------------- launch ----------------
extern "C" void kernel_launch(void* const* d_in, const int* in_sizes, int n_in,
                              void* d_out, int out_size, void* d_ws, size_t ws_size,
                              hipStream_t stream) {
    (void)in_sizes; (void)n_in; (void)out_size; (void)ws_size;
    const float* inp = (const float*)d_in[0];
    const float* x   = (const float*)d_in[1];
    const float* y   = (const float*)d_in[2];
    const float* Wq  = (const float*)d_in[3];
    const float* bq  = (const float*)d_in[4];
    const float* Wk  = (const float*)d_in[5];
    const float* bk  = (const float*)d_in[6];
    const float* Wv  = (const float*)d_in[7];
    const float* bv  = (const float*)d_in[8];
    const float* Wc  = (const float*)d_in[9];
    const float* bc  = (const float*)d_in[10];
    const float* alpha = (const float*)d_in[11];
    const float* beta  = (const float*)d_in[12];
    float* out = (float*)d_out;

    char* ws = (char*)d_ws;
    u16* xT   = (u16*)(ws + OFF_XT);
    u16* yT   = (u16*)(ws + OFF_YT);
    u16* pjx  = (u16*)(ws + OFF_PJX);
    u16* pjy  = (u16*)(ws + OFF_PJY);
    u16* pv   = (u16*)(ws + OFF_PV);
    u16* ad   = (u16*)(ws + OFF_AD);
    u16* attn = (u16*)(ws + OFF_ATTN);
    u16* catT = (u16*)(ws + OFF_CATT);
    u16* wqk  = (u16*)(ws + OFF_WQK);
    u16* wv   = (u16*)(ws + OFF_WV);
    u16* wt   = (u16*)(ws + OFF_WT);
    float* sA  = (float*)(ws + OFF_SA);
    float* oA  = (float*)(ws + OFF_OA);
    float* tmA = (float*)(ws + OFF_TM);

    hipMemsetAsync(catT, 0, SZ_CATT, stream);   // zero border = SAME padding
    k_prep_w<<<1024, 256, 0, stream>>>(Wq, Wk, Wv, wqk, wv);
    k_prep_wt<<<2048, 256, 0, stream>>>(Wc, wt);
    k_stats<<<8192, 256, 0, stream>>>(x, inp, sA, oA, tmA);
    k_transpose<<<dim3(128, 16, 2), 256, 0, stream>>>(x, y, xT, yT);
    k_adain<<<8192, 256, 0, stream>>>(inp, sA, oA, ad);
    k_proj<<<dim3(8, 16, 2), 256, 0, stream>>>(xT, yT, wqk, bq, bk, pjx, pjy);
    k_pv<<<dim3(8, 4, 16), 256, 0, stream>>>(xT, wv, bv, pv);
    // identity attention: Q from x, K from y
    k_score<<<256, 256, 0, stream>>>(pjx, pjy, attn);
    k_value<0><<<dim3(8, 4, 16), 256, 0, stream>>>(attn, pv, xT, tmA, beta, catT);
    // pose attention: Q from y, K from x
    k_score<<<256, 256, 0, stream>>>(pjy, pjx, attn);
    k_value<1><<<dim3(8, 4, 16), 256, 0, stream>>>(attn, ad, xT, tmA, alpha, catT);
    k_conv<<<dim3(4, 8, 16), 256, 0, stream>>>(wt, catT, bc, out);
}

// Round 3
// 465.374 us; speedup vs baseline: 1.8337x; 1.0370x over previous
//
#include <hip/hip_runtime.h>

typedef unsigned short u16;
typedef unsigned int u32;

using bf16x8 = __attribute__((ext_vector_type(8))) __bf16;
using f32x4  = __attribute__((ext_vector_type(4))) float;
using u16x4  = __attribute__((ext_vector_type(4))) unsigned short;

__device__ __forceinline__ f32x4 MFMA(bf16x8 a, bf16x8 b, f32x4 c) {
    return __builtin_amdgcn_mfma_f32_16x16x32_bf16(a, b, c, 0, 0, 0);
}

__device__ __forceinline__ u16 f2bf(float f) {
    u32 u = __builtin_bit_cast(u32, f);
    u = (u + 0x7FFFu + ((u >> 16) & 1u)) >> 16;
    return (u16)u;
}
__device__ __forceinline__ float bf2f(u16 h) {
    return __builtin_bit_cast(float, (u32)h << 16);
}

typedef const __attribute__((address_space(1))) unsigned int* gp_t;
typedef __attribute__((address_space(3))) unsigned int* lp_t;

__device__ __forceinline__ void gload16(const void* g, void* l) {
    __builtin_amdgcn_global_load_lds((gp_t)g, (lp_t)l, 16, 0, 0);
}

// ---------------- constants ----------------
#define NPADR  1156   // 34*34

// workspace layout (bytes)
static constexpr size_t OFF_XT   = 0;
static constexpr size_t OFF_YT   = OFF_XT  + (size_t)16*1024*512*2;
static constexpr size_t OFF_PJX  = OFF_YT  + (size_t)16*1024*512*2;
static constexpr size_t OFF_PJY  = OFF_PJX + (size_t)16*1024*128*2;
static constexpr size_t OFF_PV   = OFF_PJY + (size_t)16*1024*128*2;
static constexpr size_t OFF_AD   = OFF_PV  + (size_t)16*512*1024*2;
static constexpr size_t OFF_ATTN = OFF_AD  + (size_t)16*512*1024*2;
static constexpr size_t OFF_ATT2 = OFF_ATTN+ (size_t)16*1024*1024*2;
static constexpr size_t OFF_CATT = OFF_ATT2+ (size_t)16*1024*1024*2;
static constexpr size_t OFF_WQK  = OFF_CATT+ (size_t)16*1156*1024*2;
static constexpr size_t OFF_WV   = OFF_WQK + (size_t)128*512*2;
static constexpr size_t OFF_WT   = OFF_WV  + (size_t)512*512*2;
static constexpr size_t OFF_SA   = OFF_WT  + (size_t)9*512*1024*2;
static constexpr size_t OFF_OA   = OFF_SA  + (size_t)16*512*4;
static constexpr size_t OFF_TM   = OFF_OA  + (size_t)16*512*4;
static constexpr size_t SZ_CATT  = (size_t)16*1156*1024*2;

// ---------------- weight prep ----------------
__global__ __launch_bounds__(256) void k_prep_w(const float* __restrict__ Wq,
                                                const float* __restrict__ Wk,
                                                const float* __restrict__ Wv,
                                                u16* __restrict__ wqk, u16* __restrict__ wv) {
    int i = blockIdx.x * 256 + threadIdx.x;
    if (i < 128 * 512) {
        float v = (i < 64 * 512) ? Wq[i] : Wk[i - 64 * 512];
        wqk[i] = f2bf(v);
    }
    if (i < 512 * 512) wv[i] = f2bf(Wv[i]);
}

__global__ __launch_bounds__(256) void k_prep_wt(const float* __restrict__ Wc, u16* __restrict__ wt) {
    int e = blockIdx.x * 256 + threadIdx.x;
    const float* src = Wc + (size_t)e * 9;
#pragma unroll
    for (int tap = 0; tap < 9; tap++) wt[(size_t)tap * 524288 + e] = f2bf(src[tap]);
}

// ---------------- stats ----------------
__global__ __launch_bounds__(256) void k_stats(const float* __restrict__ x, const float* __restrict__ inp,
                                               float* __restrict__ sA, float* __restrict__ oA,
                                               float* __restrict__ tmA) {
    int row = blockIdx.x;
    int t = threadIdx.x;
    const float4* xr = (const float4*)(x + (size_t)row * 1024);
    const float4* ir = (const float4*)(inp + (size_t)row * 1024);
    float4 a = xr[t], c = ir[t];
    float s1 = a.x + a.y + a.z + a.w;
    float s2 = a.x * a.x + a.y * a.y + a.z * a.z + a.w * a.w;
    float p1 = c.x + c.y + c.z + c.w;
    float p2 = c.x * c.x + c.y * c.y + c.z * c.z + c.w * c.w;
#pragma unroll
    for (int m = 32; m; m >>= 1) {
        s1 += __shfl_xor(s1, m); s2 += __shfl_xor(s2, m);
        p1 += __shfl_xor(p1, m); p2 += __shfl_xor(p2, m);
    }
    __shared__ float red[4][4];
    int wv = t >> 6;
    if ((t & 63) == 0) { red[wv][0] = s1; red[wv][1] = s2; red[wv][2] = p1; red[wv][3] = p2; }
    __syncthreads();
    if (t == 0) {
        s1 = red[0][0] + red[1][0] + red[2][0] + red[3][0];
        s2 = red[0][1] + red[1][1] + red[2][1] + red[3][1];
        p1 = red[0][2] + red[1][2] + red[2][2] + red[3][2];
        p2 = red[0][3] + red[1][3] + red[2][3] + red[3][3];
        float tm = s1 * (1.0f / 1024.0f);
        float ts = sqrtf((s2 - 1024.0f * tm * tm) * (1.0f / 1023.0f) + 1e-5f);
        float im = p1 * (1.0f / 1024.0f);
        float is = sqrtf((p2 - 1024.0f * im * im) * (1.0f / 1023.0f) + 1e-5f);
        float sc = ts / is;
        sA[row] = sc; oA[row] = tm - im * sc; tmA[row] = tm;
    }
}

// ---------------- transpose x,y -> bf16 [n][c] ----------------
__global__ __launch_bounds__(256) void k_transpose(const float* __restrict__ x, const float* __restrict__ y,
                                                   u16* __restrict__ xT, u16* __restrict__ yT) {
    __shared__ float tile[64][65];
    int b = blockIdx.y;
    int ct = blockIdx.x >> 4;
    int nt = blockIdx.x & 15;
    const float* src = blockIdx.z ? y : x;
    u16* dst = blockIdx.z ? yT : xT;
    int c0 = ct * 64, n0 = nt * 64;
    int ln = threadIdx.x & 63, wv = threadIdx.x >> 6;
#pragma unroll
    for (int i = 0; i < 16; i++) {
        int cl = wv + i * 4;
        tile[cl][ln] = src[((size_t)(b * 512 + c0 + cl)) * 1024 + n0 + ln];
    }
    __syncthreads();
#pragma unroll
    for (int i = 0; i < 16; i++) {
        int nl = wv + i * 4;
        dst[((size_t)(b * 1024 + n0 + nl)) * 512 + c0 + ln] = f2bf(tile[ln][nl]);
    }
}

// ---------------- adained = inp*s + o ----------------
__global__ __launch_bounds__(256) void k_adain(const float* __restrict__ inp, const float* __restrict__ sA,
                                               const float* __restrict__ oA, u16* __restrict__ ad) {
    size_t i = ((size_t)blockIdx.x * 256 + threadIdx.x) * 4;
    int row = (int)(i >> 10);
    float sc = sA[row], of = oA[row];
    float4 v = *(const float4*)(inp + i);
    u16x4 r;
    r[0] = f2bf(v.x * sc + of); r[1] = f2bf(v.y * sc + of);
    r[2] = f2bf(v.z * sc + of); r[3] = f2bf(v.w * sc + of);
    *(u16x4*)(ad + i) = r;
}

// ---------------- projections ----------------
__global__ __launch_bounds__(256) void k_proj(const u16* __restrict__ xT, const u16* __restrict__ yT,
                                              const u16* __restrict__ wqk, const float* __restrict__ bq,
                                              const float* __restrict__ bk, u16* __restrict__ pjx,
                                              u16* __restrict__ pjy) {
    int b = blockIdx.y;
    const u16* S = blockIdx.z ? yT : xT;
    u16* D = blockIdx.z ? pjy : pjx;
    int l = threadIdx.x & 63, w = threadIdx.x >> 6;
    int lr = l & 15, lg = l >> 4;
    int wm = (w >> 1) * 64;
    int nb = blockIdx.x * 128 + (w & 1) * 64;
    f32x4 zero = {0.f, 0.f, 0.f, 0.f};
    f32x4 acc[4][4];
#pragma unroll
    for (int i = 0; i < 4; i++)
#pragma unroll
        for (int j = 0; j < 4; j++) acc[i][j] = zero;
    const u16* Sbase = S + ((size_t)b * 1024 + nb + lr) * 512 + lg * 8;
    for (int kk = 0; kk < 512; kk += 32) {
        bf16x8 af[4], bb[4];
#pragma unroll
        for (int ri = 0; ri < 4; ri++)
            af[ri] = *(const bf16x8*)(wqk + (size_t)(wm + 16 * ri + lr) * 512 + kk + lg * 8);
#pragma unroll
        for (int ci = 0; ci < 4; ci++)
            bb[ci] = *(const bf16x8*)(Sbase + (size_t)(16 * ci) * 512 + kk);
#pragma unroll
        for (int ri = 0; ri < 4; ri++)
#pragma unroll
            for (int ci = 0; ci < 4; ci++) acc[ri][ci] = MFMA(af[ri], bb[ci], acc[ri][ci]);
    }
#pragma unroll
    for (int ri = 0; ri < 4; ri++) {
#pragma unroll
        for (int r = 0; r < 4; r++) {
            int cq = wm + 16 * ri + 4 * lg + r;
            float bias = (cq < 64) ? bq[cq] : bk[cq - 64];
#pragma unroll
            for (int ci = 0; ci < 4; ci++) {
                int n = nb + 16 * ci + lr;
                D[((size_t)b * 1024 + n) * 128 + cq] = f2bf(acc[ri][ci][r] + bias);
            }
        }
    }
}

// ---------------- pipelined 128x128 GEMM core (counted vmcnt, 3-slot) ----------------
// A: [M][K] (LDA), B: [N][K] (LDB); C = A * B^T.  LDS slot: [4 kgroup][128 row][16B].
template <int KTOT, int LDA, int LDB>
__device__ __forceinline__ void gemm128(const u16* __restrict__ Aorig, const u16* __restrict__ Borig,
                                        f32x4 (&acc)[4][4]) {
    __shared__ __align__(16) u16 lds[24576];  // A: 3x8KB @0 ; B: 3x8KB @24KB
    constexpr int NT = KTOT / 32;
    const int tid = threadIdx.x;
    const int l = tid & 63, w = tid >> 6;
    const int lr = l & 15, lg = l >> 4;
    const int moff = (w >> 1) * 64, coff = (w & 1) * 64;
    char* ldsb = (char*)lds;
    auto stage = [&](const u16* orig, int ldx, int bufByte) {
#pragma unroll
        for (int it = 0; it < 2; it++) {
            int slot = it * 256 + tid;
            gload16(orig + (size_t)(slot & 127) * ldx + (slot >> 7) * 8,
                    ldsb + bufByte + it * 4096 + w * 1024);
        }
    };
    auto stageT = [&](int t, int s) {
        stage(Aorig + t * 32, LDA, s * 8192);
        stage(Borig + t * 32, LDB, 24576 + s * 8192);
    };
    stageT(0, 0);
    stageT(1, 1);
    int rs = 0;
#pragma unroll 1
    for (int q = 0; q < NT; q++) {
        int qq = q + 2; if (qq >= NT) qq -= NT;
        int ss = rs + 2; if (ss >= 3) ss -= 3;
        stageT(qq, ss);
        asm volatile("s_waitcnt vmcnt(8)" ::: "memory");
        __builtin_amdgcn_s_barrier();
        const char* A = ldsb + rs * 8192;
        const char* B = ldsb + 24576 + rs * 8192;
        bf16x8 af[4], bb[4];
#pragma unroll
        for (int i = 0; i < 4; i++) af[i] = *(const bf16x8*)(A + lg * 2048 + (moff + 16 * i + lr) * 16);
#pragma unroll
        for (int i = 0; i < 4; i++) bb[i] = *(const bf16x8*)(B + lg * 2048 + (coff + 16 * i + lr) * 16);
        __builtin_amdgcn_s_setprio(1);
#pragma unroll
        for (int ri = 0; ri < 4; ri++)
#pragma unroll
            for (int ci = 0; ci < 4; ci++) acc[ri][ci] = MFMA(af[ri], bb[ci], acc[ri][ci]);
        __builtin_amdgcn_s_setprio(0);
        __builtin_amdgcn_s_barrier();
        rs = (rs + 1 == 3) ? 0 : rs + 1;
    }
    asm volatile("s_waitcnt vmcnt(0)" ::: "memory");
}

// ---------------- pv = Wv @ x + bv ----------------
__global__ __launch_bounds__(256) void k_pv(const u16* __restrict__ xT, const u16* __restrict__ wv,
                                            const float* __restrict__ bv, u16* __restrict__ pv) {
    int b = blockIdx.z;
    int mb = blockIdx.y * 128;
    int nb = blockIdx.x * 128;
    f32x4 acc[4][4];
#pragma unroll
    for (int i = 0; i < 4; i++)
#pragma unroll
        for (int j = 0; j < 4; j++) acc[i][j] = f32x4{0.f, 0.f, 0.f, 0.f};
    gemm128<512, 512, 512>(wv + (size_t)mb * 512, xT + ((size_t)b * 1024 + nb) * 512, acc);
    int l = threadIdx.x & 63, w = threadIdx.x >> 6;
    int lr = l & 15, lg = l >> 4;
    int moff = (w >> 1) * 64, coff = (w & 1) * 64;
#pragma unroll
    for (int ri = 0; ri < 4; ri++) {
#pragma unroll
        for (int r = 0; r < 4; r++) {
            int co = mb + moff + 16 * ri + 4 * lg + r;
            float bias = bv[co];
#pragma unroll
            for (int ci = 0; ci < 4; ci++) {
                int n = nb + coff + 16 * ci + lr;
                pv[((size_t)b * 512 + co) * 1024 + n] = f2bf(acc[ri][ci][r] + bias);
            }
        }
    }
}

// ---------------- score + softmax, both directions in one launch ----------------
__global__ __launch_bounds__(256) void k_score(const u16* __restrict__ pjx, const u16* __restrict__ pjy,
                                               u16* __restrict__ attnA, u16* __restrict__ attnB) {
    const u16* qT = blockIdx.y ? pjy : pjx;
    const u16* kT = blockIdx.y ? pjx : pjy;
    u16* attn = blockIdx.y ? attnB : attnA;
    int g = blockIdx.x * 4 + (threadIdx.x >> 6);
    int b = g >> 6, rb = g & 63;
    int l = threadIdx.x & 63, lr = l & 15, lg = l >> 4;
    int mb = rb * 16;
    const u16* qbase = qT + ((size_t)b * 1024 + mb + lr) * 128 + lg * 8;
    bf16x8 a0 = *(const bf16x8*)(qbase);
    bf16x8 a1 = *(const bf16x8*)(qbase + 32);
    const u16* kbase = kT + ((size_t)b * 1024 + lr) * 128 + 64 + lg * 8;
    f32x4 zero = {0.f, 0.f, 0.f, 0.f};
    float mrun[4] = {-1e30f, -1e30f, -1e30f, -1e30f};
    float srun[4] = {0.f, 0.f, 0.f, 0.f};
    for (int cf = 0; cf < 64; cf++) {
        bf16x8 b0 = *(const bf16x8*)(kbase + (size_t)cf * 16 * 128);
        bf16x8 b1 = *(const bf16x8*)(kbase + (size_t)cf * 16 * 128 + 32);
        f32x4 acc = zero;
        acc = MFMA(a0, b0, acc);
        acc = MFMA(a1, b1, acc);
#pragma unroll
        for (int r = 0; r < 4; r++) {
            float v = acc[r] * 0.125f;
            float mn = fmaxf(mrun[r], v);
            srun[r] = srun[r] * __expf(mrun[r] - mn) + __expf(v - mn);
            mrun[r] = mn;
        }
    }
#pragma unroll
    for (int m = 1; m < 16; m <<= 1) {
#pragma unroll
        for (int r = 0; r < 4; r++) {
            float mo = __shfl_xor(mrun[r], m);
            float so = __shfl_xor(srun[r], m);
            float mn = fmaxf(mrun[r], mo);
            srun[r] = srun[r] * __expf(mrun[r] - mn) + so * __expf(mo - mn);
            mrun[r] = mn;
        }
    }
    float inv[4];
#pragma unroll
    for (int r = 0; r < 4; r++) inv[r] = 1.0f / srun[r];
    for (int cf = 0; cf < 64; cf++) {
        bf16x8 b0 = *(const bf16x8*)(kbase + (size_t)cf * 16 * 128);
        bf16x8 b1 = *(const bf16x8*)(kbase + (size_t)cf * 16 * 128 + 32);
        f32x4 acc = zero;
        acc = MFMA(a0, b0, acc);
        acc = MFMA(a1, b1, acc);
#pragma unroll
        for (int r = 0; r < 4; r++) {
            float v = __expf(acc[r] * 0.125f - mrun[r]) * inv[r];
            attn[((size_t)b * 1024 + mb + 4 * lg + r) * 1024 + cf * 16 + lr] = f2bf(v);
        }
    }
}

// ---------------- value GEMMs (both variants in one launch) -> catT ----------------
__global__ __launch_bounds__(256) void k_value(const u16* __restrict__ attnA, const u16* __restrict__ attnB,
                                               const u16* __restrict__ pv, const u16* __restrict__ ad,
                                               const u16* __restrict__ xT, const float* __restrict__ tmA,
                                               const float* __restrict__ alpha, const float* __restrict__ beta,
                                               u16* __restrict__ catT) {
    int z = blockIdx.z;
    int b = z & 15, var = z >> 4;
    const u16* attn = var ? attnB : attnA;
    const u16* V = var ? ad : pv;
    int mb = blockIdx.x * 128;
    int cb = blockIdx.y * 128;
    f32x4 acc[4][4];
#pragma unroll
    for (int i = 0; i < 4; i++)
#pragma unroll
        for (int j = 0; j < 4; j++) acc[i][j] = f32x4{0.f, 0.f, 0.f, 0.f};
    gemm128<1024, 1024, 1024>(attn + ((size_t)b * 1024 + mb) * 1024,
                              V + ((size_t)b * 512 + cb) * 1024, acc);
    int l = threadIdx.x & 63, w = threadIdx.x >> 6;
    int lr = l & 15, lg = l >> 4;
    int moff = (w >> 1) * 64, coff = (w & 1) * 64;
    float sc = var ? alpha[0] : beta[0];
#pragma unroll
    for (int ri = 0; ri < 4; ri++) {
#pragma unroll
        for (int r = 0; r < 4; r++) {
            int m = mb + moff + 16 * ri + 4 * lg + r;
            int pidx = ((m >> 5) + 1) * 34 + (m & 31) + 1;
#pragma unroll
            for (int ci = 0; ci < 4; ci++) {
                int c = cb + coff + 16 * ci + lr;
                float av = acc[ri][ci][r];
                float res;
                if (var == 0) {
                    float xv = bf2f(xT[((size_t)b * 1024 + m) * 512 + c]);
                    res = (1.f - sc) * xv + sc * av;
                } else {
                    float tm = tmA[b * 512 + c];
                    float adv = bf2f(V[((size_t)b * 512 + c) * 1024 + m]);
                    res = (1.f - sc) * (1024.f * tm - av) + sc * adv;
                }
                catT[((size_t)b * NPADR + pidx) * 1024 + (var ? 512 : 0) + c] = f2bf(res);
            }
        }
    }
}

// ---------------- 3x3 conv: counted-vmcnt pipelined implicit GEMM ----------------
// A (weights) triple-buffered 3x8KB; B (catT halo) double-buffered 2x16KB.
// Phase q = ckI*9+tap: issue A(q+2); issue B(ck+1) at tap 6; vmcnt(4|8); barrier;
// 16 MFMA; barrier.  vmcnt never 0 in the loop.
__global__ __launch_bounds__(256) void k_conv(const u16* __restrict__ wt, const u16* __restrict__ catT,
                                              const float* __restrict__ bc, float* __restrict__ out) {
    __shared__ __align__(16) u16 lds[28672];  // A: 3x8KB @0 ; B: 2x16KB @24KB
    char* ldsb = (char*)lds;
    const int tid = threadIdx.x;
    const int l = tid & 63, w = tid >> 6;
    const int lr = l & 15, lg = l >> 4;
    const int b = blockIdx.z;
    const int ob = blockIdx.x * 128;
    const int pb = blockIdx.y * 128;
    const int r0 = blockIdx.y * 4;
    const int ooff = (w >> 1) * 64, poff = (w & 1) * 64;
    const u16* catB = catT + (size_t)b * NPADR * 1024 + (size_t)r0 * 34 * 1024;

    auto stageB = [&](int ckb, int bsel) {
        char* base = ldsb + 24576 + bsel * 16384;
        const u16* src0 = catB + ckb;
#pragma unroll
        for (int it = 0; it < 4; it++) {
            if (tid < 204)
                gload16(src0 + (size_t)tid * 1024 + it * 8, base + it * 4096 + w * 1024);
        }
    };
    auto stageA = [&](int tap, int ckb, int slotByte) {
        char* base = ldsb + slotByte;
        const u16* src0 = wt + ((size_t)tap * 512 + ob) * 1024 + ckb;
#pragma unroll
        for (int it = 0; it < 2; it++) {
            int slot = it * 256 + tid;
            gload16(src0 + (size_t)(slot & 127) * 1024 + (slot >> 7) * 8,
                    base + it * 4096 + w * 1024);
        }
    };

    int aoff[4], rbase[4];
#pragma unroll
    for (int i = 0; i < 4; i++) {
        aoff[i] = lg * 2048 + (ooff + 16 * i + lr) * 16;
        int p = poff + 16 * i + lr;
        rbase[i] = ((p >> 5) + 1) * 34 + (p & 31) + 1;
    }

    f32x4 acc[4][4];
#pragma unroll
    for (int i = 0; i < 4; i++)
#pragma unroll
        for (int j = 0; j < 4; j++) acc[i][j] = f32x4{0.f, 0.f, 0.f, 0.f};

    // prologue: A(phase0), B(ck0), A(phase1)  -> at phase0, vmcnt(4) leaves exactly A2,A3 pending
    stageA(0, 0, 0);
    stageB(0, 0);
    stageA(1, 0, 8192);
#pragma unroll 1
    for (int ckI = 0; ckI < 32; ckI++) {
#pragma unroll
        for (int tap = 0; tap < 9; tap++) {
            // issue A for phase q+2 (slot (tap+2)%3 since 9 % 3 == 0)
            {
                const int t2 = (tap + 2) % 9;
                int c2 = (tap >= 7) ? ckI + 1 : ckI;
                if (c2 >= 32) c2 = 0;  // wrap: benign dummy restage
                stageA(t2, c2 * 32, ((tap + 2) % 3) * 8192);
            }
            if (tap == 6) {
                int cn = ckI + 1;
                int cd = (cn >= 32) ? 0 : cn;
                stageB(cd * 32, cn & 1);
            }
            // queue arithmetic: loads issued after A(q) = 4 (taps 0-5) or 8 (taps 6-8)
            if (tap >= 6) asm volatile("s_waitcnt vmcnt(8)" ::: "memory");
            else          asm volatile("s_waitcnt vmcnt(4)" ::: "memory");
            __builtin_amdgcn_s_barrier();
            const char* A = ldsb + (tap % 3) * 8192;
            const char* B = ldsb + 24576 + (ckI & 1) * 16384;
            const int drow = (tap / 3 - 1) * 34 + (tap % 3 - 1);
            bf16x8 af[4], bb[4];
#pragma unroll
            for (int i = 0; i < 4; i++) af[i] = *(const bf16x8*)(A + aoff[i]);
#pragma unroll
            for (int i = 0; i < 4; i++) bb[i] = *(const bf16x8*)(B + lg * 4096 + (rbase[i] + drow) * 16);
            __builtin_amdgcn_s_setprio(1);
#pragma unroll
            for (int ri = 0; ri < 4; ri++)
#pragma unroll
                for (int ci = 0; ci < 4; ci++) acc[ri][ci] = MFMA(af[ri], bb[ci], acc[ri][ci]);
            __builtin_amdgcn_s_setprio(0);
            __builtin_amdgcn_s_barrier();
        }
    }
    asm volatile("s_waitcnt vmcnt(0)" ::: "memory");
#pragma unroll
    for (int ri = 0; ri < 4; ri++) {
#pragma unroll
        for (int r = 0; r < 4; r++) {
            int o = ob + ooff + 16 * ri + 4 * lg + r;
            float bias = bc[o];
#pragma unroll
            for (int ci = 0; ci < 4; ci++) {
                int p = pb + poff + 16 * ci + lr;
                float v = acc[ri][ci][r] + bias;
                v = (v >= 0.f) ? v : 0.2f * v;
                out[((size_t)b * 512 + o) * 1024 + p] = v;
            }
        }
    }
}

// ---------------- launch ----------------
extern "C" void kernel_launch(void* const* d_in, const int* in_sizes, int n_in,
                              void* d_out, int out_size, void* d_ws, size_t ws_size,
                              hipStream_t stream) {
    (void)in_sizes; (void)n_in; (void)out_size; (void)ws_size;
    const float* inp = (const float*)d_in[0];
    const float* x   = (const float*)d_in[1];
    const float* y   = (const float*)d_in[2];
    const float* Wq  = (const float*)d_in[3];
    const float* bq  = (const float*)d_in[4];
    const float* Wk  = (const float*)d_in[5];
    const float* bk  = (const float*)d_in[6];
    const float* Wv  = (const float*)d_in[7];
    const float* bv  = (const float*)d_in[8];
    const float* Wc  = (const float*)d_in[9];
    const float* bc  = (const float*)d_in[10];
    const float* alpha = (const float*)d_in[11];
    const float* beta  = (const float*)d_in[12];
    float* out = (float*)d_out;

    char* ws = (char*)d_ws;
    u16* xT   = (u16*)(ws + OFF_XT);
    u16* yT   = (u16*)(ws + OFF_YT);
    u16* pjx  = (u16*)(ws + OFF_PJX);
    u16* pjy  = (u16*)(ws + OFF_PJY);
    u16* pv   = (u16*)(ws + OFF_PV);
    u16* ad   = (u16*)(ws + OFF_AD);
    u16* attnA = (u16*)(ws + OFF_ATTN);
    u16* attnB = (u16*)(ws + OFF_ATT2);
    u16* catT = (u16*)(ws + OFF_CATT);
    u16* wqk  = (u16*)(ws + OFF_WQK);
    u16* wv   = (u16*)(ws + OFF_WV);
    u16* wt   = (u16*)(ws + OFF_WT);
    float* sA  = (float*)(ws + OFF_SA);
    float* oA  = (float*)(ws + OFF_OA);
    float* tmA = (float*)(ws + OFF_TM);

    hipMemsetAsync(catT, 0, SZ_CATT, stream);   // zero border = SAME padding
    k_prep_w<<<1024, 256, 0, stream>>>(Wq, Wk, Wv, wqk, wv);
    k_prep_wt<<<2048, 256, 0, stream>>>(Wc, wt);
    k_stats<<<8192, 256, 0, stream>>>(x, inp, sA, oA, tmA);
    k_transpose<<<dim3(128, 16, 2), 256, 0, stream>>>(x, y, xT, yT);
    k_adain<<<8192, 256, 0, stream>>>(inp, sA, oA, ad);
    k_proj<<<dim3(8, 16, 2), 256, 0, stream>>>(xT, yT, wqk, bq, bk, pjx, pjy);
    k_pv<<<dim3(8, 4, 16), 256, 0, stream>>>(xT, wv, bv, pv);
    k_score<<<dim3(256, 2), 256, 0, stream>>>(pjx, pjy, attnA, attnB);
    k_value<<<dim3(8, 4, 32), 256, 0, stream>>>(attnA, attnB, pv, ad, xT, tmA, alpha, beta, catT);
    k_conv<<<dim3(4, 8, 16), 256, 0, stream>>>(wt, catT, bc, out);
}